// Round 3
// baseline (651.574 us; speedup 1.0000x reference)
//
#include <hip/hip_runtime.h>
#include <math.h>

// ---------------------------------------------------------------------------
// YOLOV3TargetMerger — single fused kernel.
// Block = 256 threads handles 256 anchor rows of one batch element:
//   phase 1: per-row obj/centers/scales/weights (+ IOU max vs 50 gt in LDS)
//   phase 2: 20 coalesced float4 iterations over the block's class slab
// mask (obj_t > 0) is computed once per row, staged in LDS for phase 2.
// Streaming class traffic (233 MB read, 466 MB write, zero reuse) uses
// non-temporal load/store (native ext_vector_type — HIP float4 is a class
// and the builtin rejects it) to keep it out of L2.
// Floor: 486 MB writes + ~140 MB predicated reads ~= 99 us @ 6.3 TB/s.
// ---------------------------------------------------------------------------

typedef float nfloat4 __attribute__((ext_vector_type(4)));

__global__ __launch_bounds__(256) void yolo_fused_kernel(
    const float4* __restrict__ bp,      // [b*N] box_preds
    const float4* __restrict__ gt,      // [b*M] gt_boxes
    const float*  __restrict__ obj_t,   // [b*N]
    const float2* __restrict__ cen,     // [b*N]
    const float2* __restrict__ scl,     // [b*N]
    const float2* __restrict__ wt,      // [b*N]
    const nfloat4* __restrict__ clas,   // [b*N*20]
    float*  __restrict__ out_obj,
    float2* __restrict__ out_cen,
    float2* __restrict__ out_scl,
    float2* __restrict__ out_wt,
    nfloat4* __restrict__ out_ct,
    nfloat4* __restrict__ out_cm,
    int N, int M)
{
    // fp contract OFF: >0.7 threshold on max-IOU is discontinuous; keep
    // mul/add sequencing identical to the numpy fp32 reference.
    #pragma clang fp contract(off)
    __shared__ float4 sgt[64];
    __shared__ unsigned char smask[256];

    const int bb = blockIdx.y;
    if ((int)threadIdx.x < M) sgt[threadIdx.x] = gt[bb * M + threadIdx.x];
    __syncthreads();

    const int n0 = blockIdx.x * 256;
    const int n  = n0 + (int)threadIdx.x;
    bool mask = false;

    if (n < N) {
        const int idx  = bb * N + n;
        const float o  = obj_t[idx];
        mask = o > 0.0f;

        float objv = o;
        if (!mask) {
            const float4 p      = bp[idx];
            const float  area_p = (p.z - p.x) * (p.w - p.y);
            float m = -INFINITY;
            for (int j = 0; j < M; ++j) {
                const float4 g    = sgt[j];
                const float tlx   = fmaxf(p.x, g.x);
                const float tly   = fmaxf(p.y, g.y);
                const float brx   = fminf(p.z, g.z);
                const float bry   = fminf(p.w, g.w);
                const float w     = fmaxf(brx - tlx, 0.0f);
                const float h     = fmaxf(bry - tly, 0.0f);
                const float inter = w * h;
                const float area_g = (g.z - g.x) * (g.w - g.y);
                const float uni   = (area_p + area_g) - inter;
                const float iou   = inter / (uni + 1e-12f);
                m = fmaxf(m, iou);
            }
            objv = (m > 0.7f) ? -1.0f : 0.0f;
        }

        out_obj[idx] = objv;
        const float2 z2 = make_float2(0.0f, 0.0f);
        out_cen[idx] = mask ? cen[idx] : z2;
        out_scl[idx] = mask ? scl[idx] : z2;
        out_wt[idx]  = mask ? wt[idx]  : z2;
    }

    smask[threadIdx.x] = mask ? 1 : 0;
    __syncthreads();

    // ---- class phase: this block's slab is rows [n0, n0+rows) of batch bb,
    // i.e. float4 indices base .. base + rows*20, fully coalesced.
    const int rows   = min(256, N - n0);
    const int count4 = rows * 20;
    const int base   = (bb * N + n0) * 20;   // max ~14.6M, fits int

    for (int k = (int)threadIdx.x; k < count4; k += 256) {
        const int  lrow = k / 20;            // magic-mul, cheap
        const bool m2   = smask[lrow] != 0;
        const int  gi   = base + k;

        nfloat4 ct = {-1.0f, -1.0f, -1.0f, -1.0f};
        if (m2) ct = __builtin_nontemporal_load(&clas[gi]);

        nfloat4 cm;
        cm.x = (m2 && (ct.x >= 0.0f)) ? 1.0f : 0.0f;
        cm.y = (m2 && (ct.y >= 0.0f)) ? 1.0f : 0.0f;
        cm.z = (m2 && (ct.z >= 0.0f)) ? 1.0f : 0.0f;
        cm.w = (m2 && (ct.w >= 0.0f)) ? 1.0f : 0.0f;

        __builtin_nontemporal_store(ct, &out_ct[gi]);
        __builtin_nontemporal_store(cm, &out_cm[gi]);
    }
}

extern "C" void kernel_launch(void* const* d_in, const int* in_sizes, int n_in,
                              void* d_out, int out_size, void* d_ws, size_t ws_size,
                              hipStream_t stream) {
    const float* box_preds = (const float*)d_in[0];
    const float* gt_boxes  = (const float*)d_in[1];
    const float* obj_t     = (const float*)d_in[2];
    const float* centers_t = (const float*)d_in[3];
    const float* scales_t  = (const float*)d_in[4];
    const float* weights_t = (const float*)d_in[5];
    const float* clas_t    = (const float*)d_in[6];

    const int b  = 32;                    // per reference setup_inputs()
    const int bN = in_sizes[2];           // obj_t is [b,N,1] -> b*N
    const int N  = bN / b;
    const int M  = in_sizes[1] / (b * 4); // gt_boxes [b,M,4]

    // Outputs concatenated flat in return order.
    float*  out     = (float*)d_out;
    float*  out_obj = out;                               // [bN]
    float2* out_cen = (float2*)(out + (size_t)1  * bN);  // [bN,2]
    float2* out_scl = (float2*)(out + (size_t)3  * bN);  // [bN,2]
    float2* out_wt  = (float2*)(out + (size_t)5  * bN);  // [bN,2]
    nfloat4* out_ct = (nfloat4*)(out + (size_t)7  * bN); // [bN,80]
    nfloat4* out_cm = (nfloat4*)(out + (size_t)87 * bN); // [bN,80]

    dim3 grid((N + 255) / 256, b);
    yolo_fused_kernel<<<grid, 256, 0, stream>>>(
        (const float4*)box_preds, (const float4*)gt_boxes, obj_t,
        (const float2*)centers_t, (const float2*)scales_t,
        (const float2*)weights_t, (const nfloat4*)clas_t,
        out_obj, out_cen, out_scl, out_wt, out_ct, out_cm, N, M);
}

// Round 4
// 645.412 us; speedup vs baseline: 1.0095x; 1.0095x over previous
//
#include <hip/hip_runtime.h>
#include <math.h>

// ---------------------------------------------------------------------------
// YOLOV3TargetMerger — single fused kernel (R4: nt on all streaming traffic).
// Block = 256 threads handles 256 anchor rows of one batch element:
//   phase 1: per-row obj/centers/scales/weights (+ IOU max vs 50 gt in LDS)
//   phase 2: 20 coalesced float4 iterations over the block's class slab
// mask (obj_t > 0) staged in LDS for phase 2. All zero-reuse global traffic
// uses non-temporal load/store (native ext_vector_type; HIP float4 is a
// class the builtin rejects). Floor: 486 MB writes + ~134 MB predicated
// reads ~= 98 us @ 6.3 TB/s.
// Evidence note (R1/R3): dur_us ~650 is dominated by harness reset fills
// (~1.9 GB poison @ ~305 us each visible in rocprof); this kernel itself
// is < 305 us (absent from top-5) and estimated ~100-130 us.
// ---------------------------------------------------------------------------

typedef float nfloat4 __attribute__((ext_vector_type(4)));
typedef float nfloat2 __attribute__((ext_vector_type(2)));

__global__ __launch_bounds__(256) void yolo_fused_kernel(
    const nfloat4* __restrict__ bp,     // [b*N] box_preds
    const float4*  __restrict__ gt,     // [b*M] gt_boxes
    const float*   __restrict__ obj_t,  // [b*N]
    const nfloat2* __restrict__ cen,    // [b*N]
    const nfloat2* __restrict__ scl,    // [b*N]
    const nfloat2* __restrict__ wt,     // [b*N]
    const nfloat4* __restrict__ clas,   // [b*N*20]
    float*   __restrict__ out_obj,
    nfloat2* __restrict__ out_cen,
    nfloat2* __restrict__ out_scl,
    nfloat2* __restrict__ out_wt,
    nfloat4* __restrict__ out_ct,
    nfloat4* __restrict__ out_cm,
    int N, int M)
{
    // fp contract OFF: >0.7 threshold on max-IOU is discontinuous; keep
    // mul/add sequencing identical to the numpy fp32 reference.
    #pragma clang fp contract(off)
    __shared__ float4 sgt[64];
    __shared__ unsigned char smask[256];

    const int bb = blockIdx.y;
    if ((int)threadIdx.x < M) sgt[threadIdx.x] = gt[bb * M + threadIdx.x];
    __syncthreads();

    const int n0 = blockIdx.x * 256;
    const int n  = n0 + (int)threadIdx.x;
    bool mask = false;

    if (n < N) {
        const int idx  = bb * N + n;
        const float o  = __builtin_nontemporal_load(&obj_t[idx]);
        mask = o > 0.0f;

        float objv = o;
        if (!mask) {
            const nfloat4 p     = __builtin_nontemporal_load(&bp[idx]);
            const float  area_p = (p.z - p.x) * (p.w - p.y);
            float m = -INFINITY;
            for (int j = 0; j < M; ++j) {
                const float4 g    = sgt[j];
                const float tlx   = fmaxf(p.x, g.x);
                const float tly   = fmaxf(p.y, g.y);
                const float brx   = fminf(p.z, g.z);
                const float bry   = fminf(p.w, g.w);
                const float w     = fmaxf(brx - tlx, 0.0f);
                const float h     = fmaxf(bry - tly, 0.0f);
                const float inter = w * h;
                const float area_g = (g.z - g.x) * (g.w - g.y);
                const float uni   = (area_p + area_g) - inter;
                const float iou   = inter / (uni + 1e-12f);
                m = fmaxf(m, iou);
            }
            objv = (m > 0.7f) ? -1.0f : 0.0f;
        }

        const nfloat2 z2 = {0.0f, 0.0f};
        nfloat2 cv = z2, sv = z2, wv = z2;
        if (mask) {
            cv = __builtin_nontemporal_load(&cen[idx]);
            sv = __builtin_nontemporal_load(&scl[idx]);
            wv = __builtin_nontemporal_load(&wt[idx]);
        }
        __builtin_nontemporal_store(objv, &out_obj[idx]);
        __builtin_nontemporal_store(cv, &out_cen[idx]);
        __builtin_nontemporal_store(sv, &out_scl[idx]);
        __builtin_nontemporal_store(wv, &out_wt[idx]);
    }

    smask[threadIdx.x] = mask ? 1 : 0;
    __syncthreads();

    // ---- class phase: this block's slab is rows [n0, n0+rows) of batch bb,
    // i.e. float4 indices base .. base + rows*20, fully coalesced.
    const int rows   = min(256, N - n0);
    const int count4 = rows * 20;
    const int base   = (bb * N + n0) * 20;   // max ~14.6M, fits int

    for (int k = (int)threadIdx.x; k < count4; k += 256) {
        const int  lrow = k / 20;            // magic-mul, cheap
        const bool m2   = smask[lrow] != 0;
        const int  gi   = base + k;

        nfloat4 ct = {-1.0f, -1.0f, -1.0f, -1.0f};
        if (m2) ct = __builtin_nontemporal_load(&clas[gi]);

        nfloat4 cm;
        cm.x = (m2 && (ct.x >= 0.0f)) ? 1.0f : 0.0f;
        cm.y = (m2 && (ct.y >= 0.0f)) ? 1.0f : 0.0f;
        cm.z = (m2 && (ct.z >= 0.0f)) ? 1.0f : 0.0f;
        cm.w = (m2 && (ct.w >= 0.0f)) ? 1.0f : 0.0f;

        __builtin_nontemporal_store(ct, &out_ct[gi]);
        __builtin_nontemporal_store(cm, &out_cm[gi]);
    }
}

extern "C" void kernel_launch(void* const* d_in, const int* in_sizes, int n_in,
                              void* d_out, int out_size, void* d_ws, size_t ws_size,
                              hipStream_t stream) {
    const float* box_preds = (const float*)d_in[0];
    const float* gt_boxes  = (const float*)d_in[1];
    const float* obj_t     = (const float*)d_in[2];
    const float* centers_t = (const float*)d_in[3];
    const float* scales_t  = (const float*)d_in[4];
    const float* weights_t = (const float*)d_in[5];
    const float* clas_t    = (const float*)d_in[6];

    const int b  = 32;                    // per reference setup_inputs()
    const int bN = in_sizes[2];           // obj_t is [b,N,1] -> b*N
    const int N  = bN / b;
    const int M  = in_sizes[1] / (b * 4); // gt_boxes [b,M,4]

    // Outputs concatenated flat in return order.
    float*   out     = (float*)d_out;
    float*   out_obj = out;                               // [bN]
    nfloat2* out_cen = (nfloat2*)(out + (size_t)1  * bN); // [bN,2]
    nfloat2* out_scl = (nfloat2*)(out + (size_t)3  * bN); // [bN,2]
    nfloat2* out_wt  = (nfloat2*)(out + (size_t)5  * bN); // [bN,2]
    nfloat4* out_ct  = (nfloat4*)(out + (size_t)7  * bN); // [bN,80]
    nfloat4* out_cm  = (nfloat4*)(out + (size_t)87 * bN); // [bN,80]

    dim3 grid((N + 255) / 256, b);
    yolo_fused_kernel<<<grid, 256, 0, stream>>>(
        (const nfloat4*)box_preds, (const float4*)gt_boxes, obj_t,
        (const nfloat2*)centers_t, (const nfloat2*)scales_t,
        (const nfloat2*)weights_t, (const nfloat4*)clas_t,
        out_obj, out_cen, out_scl, out_wt, out_ct, out_cm, N, M);
}